// Round 6
// baseline (917.708 us; speedup 1.0000x reference)
//
#include <hip/hip_runtime.h>

#define HW 65536          // 256*256
#define NPOS 262144       // B(4) * HW

typedef unsigned int   u32;
typedef unsigned short u16;
typedef __attribute__((ext_vector_type(8))) short v8s;
typedef __attribute__((ext_vector_type(4))) float f32x4;

__device__ __forceinline__ float bf2f(u16 h){
  union { u32 u; float f; } c; c.u = ((u32)h) << 16; return c.f;
}
__device__ __forceinline__ u16 f2bf(float f){
  union { u32 u; float f; } c; c.f = f;
  u32 r = c.u + 0x7fffu + ((c.u >> 16) & 1u);
  return (u16)(r >> 16);
}
__device__ __forceinline__ u32 pk2(float a, float b){
  return (u32)f2bf(a) | ((u32)f2bf(b) << 16);
}
__device__ __forceinline__ v8s as8(uint4 u){
  union { uint4 a; v8s b; } c; c.a = u; return c.b;
}
__device__ __forceinline__ float gelu_exact(float x){
  return 0.5f*x*(1.0f+erff(x*0.70710678118654752f));
}

// ================= prep: spectral kernel g + LN-folded bf16 weights =================
__device__ void fold_w(const float* __restrict__ W, int rows,
                       const float* __restrict__ lw, const float* __restrict__ lb,
                       u16* __restrict__ Wf, float* __restrict__ A, float* __restrict__ B){
  int tid = threadIdx.x;
  for (int e = tid; e < rows*64; e += 256) Wf[e] = f2bf(lw[e & 63] * W[e]);
  for (int r = tid; r < rows; r += 256){
    float a = 0.f, b2 = 0.f;
    for (int c = 0; c < 64; c++){ float w = W[r*64+c]; a += lw[c]*w; b2 += lb[c]*w; }
    A[r] = a; B[r] = b2;
  }
}

__global__ void k_prep(const float* __restrict__ M, float* __restrict__ g,
    const float* wq,  const float* l1iw, const float* l1ib, u16* wqf,  float* aq,  float* bq,
    const float* wkv, const float* l1ew, const float* l1eb, u16* wkvf, float* akv, float* bkv,
    const float* wpi, const float* l2w,  const float* l2b,  u16* wpif, float* api, float* bpi,
    const float* wpa, u16* wpaf, const float* wpf, u16* wpff)
{
  int blk = blockIdx.x, tid = threadIdx.x;
  if (blk < 64){
    int t = blk*256 + tid;           // < 256*64
    int c = t >> 6, uv = t & 63, u = uv >> 3, v = uv & 7;
    const float* mc = M + c*40;
    const float ctab[8] = {1.f, 0.70710678118654752f, 0.f, -0.70710678118654752f,
                           -1.f, -0.70710678118654752f, 0.f, 0.70710678118654752f};
    float acc = 0.f;
    for (int k1=0;k1<8;k1++)
      for (int k2=0;k2<8;k2++){
        float s = (k2<=4) ? mc[k1*5+k2] : mc[(((8-k1)&7)*5) + (8-k2)];
        acc += s * ctab[(k1*u + k2*v)&7];
      }
    g[t] = acc * (1.f/64.f);
  } else if (blk == 64){ fold_w(wq, 128, l1iw, l1ib, wqf, aq, bq); }
  else if (blk == 65){ fold_w(wkv, 256, l1ew, l1eb, wkvf, akv, bkv); }
  else if (blk == 66){ fold_w(wpi, 256, l2w, l2b, wpif, api, bpi); }
  else if (blk == 67){ for (int e=tid; e<64*128; e+=256) wpaf[e] = f2bf(wpa[e]); }
  else               { for (int e=tid; e<64*128; e+=256) wpff[e] = f2bf(wpf[e]); }
}

// ================= per-pixel LN stats (mu, inv) over 64 channels =================
__global__ __launch_bounds__(256) void k_stats(
    const float* __restrict__ s0, float2* __restrict__ d0,
    const float* __restrict__ s1, float2* __restrict__ d1)
{
  const float* src = blockIdx.y ? s1 : s0;
  float2* dst = blockIdx.y ? d1 : d0;
  int p = blockIdx.x*256 + threadIdx.x;
  int b = p >> 16, hw = p & 65535;
  const float* sp = src + (size_t)b*64*HW + hw;
  float s = 0.f, q = 0.f;
  #pragma unroll
  for (int c=0;c<64;c++){ float e = sp[(size_t)c*HW]; s += e; q += e*e; }
  float mu = s*(1.f/64.f);
  float var = q*(1.f/64.f) - mu*mu;
  dst[p] = make_float2(mu, rsqrtf(fmaxf(var,0.f)+1e-5f));
}

// ================= K=64 GEMM with folded LN: dst[o] = inv*(acc - mu*A[o]) + B[o] =================
struct GA {
  const float* src; const float2* st; const u16* Wf; const float* Af; const float* Bf;
  u16* dst; int o0; int dstOff; int Cd; int b0; int pxbase;
};

__global__ __launch_bounds__(256) void k_gemm64(GA a0, GA a1){
  GA a = (blockIdx.y == 0) ? a0 : a1;
  int o0 = a.o0 + 64*blockIdx.z;
  int dstOff = a.dstOff + 64*blockIdx.z;
  __shared__ uint4 lsX[256*8];   // 32KB
  __shared__ uint4 lsW[64*8];    // 8KB
  int tid = threadIdx.x;
  int p0 = a.pxbase + blockIdx.x*256;
  int b = p0 >> 16, hwb = p0 & 65535;
  {
    const uint4* wsrc = (const uint4*)(a.Wf + (size_t)o0*64);
    #pragma unroll
    for (int i=0;i<2;i++){
      int idx = i*256 + tid, row = idx>>3, s = idx&7;
      lsW[row*8 + (s ^ (row&7))] = wsrc[idx];
    }
  }
  {
    const float* sp = a.src + (size_t)b*64*HW + hwb + tid;
    uint4* xrow = lsX + tid*8;
    #pragma unroll
    for (int sl=0; sl<8; sl++){
      float e0=sp[(size_t)(sl*8+0)*HW], e1=sp[(size_t)(sl*8+1)*HW];
      float e2=sp[(size_t)(sl*8+2)*HW], e3=sp[(size_t)(sl*8+3)*HW];
      float e4=sp[(size_t)(sl*8+4)*HW], e5=sp[(size_t)(sl*8+5)*HW];
      float e6=sp[(size_t)(sl*8+6)*HW], e7=sp[(size_t)(sl*8+7)*HW];
      uint4 pkv; pkv.x=pk2(e0,e1); pkv.y=pk2(e2,e3); pkv.z=pk2(e4,e5); pkv.w=pk2(e6,e7);
      xrow[sl ^ (tid&7)] = pkv;
    }
  }
  __syncthreads();
  int w = tid>>6, l = tid&63, g = l>>4, c15 = l&15;
  f32x4 acc[4][4];
  #pragma unroll
  for (int pp=0;pp<4;pp++)
    #pragma unroll
    for (int po=0;po<4;po++) acc[pp][po] = (f32x4){0.f,0.f,0.f,0.f};
  #pragma unroll
  for (int kk=0; kk<2; kk++){
    v8s wf[4], xf[4];
    #pragma unroll
    for (int po=0;po<4;po++){ int row = po*16 + c15; wf[po] = as8(lsW[row*8 + ((kk*4+g) ^ (row&7))]); }
    #pragma unroll
    for (int pp=0;pp<4;pp++){ int row = w*64 + pp*16 + c15; xf[pp] = as8(lsX[row*8 + ((kk*4+g) ^ (row&7))]); }
    #pragma unroll
    for (int pp=0;pp<4;pp++)
      #pragma unroll
      for (int po=0;po<4;po++)
        acc[pp][po] = __builtin_amdgcn_mfma_f32_16x16x32_bf16(wf[po], xf[pp], acc[pp][po], 0,0,0);
  }
  float2 stv[4];
  #pragma unroll
  for (int pp=0;pp<4;pp++) stv[pp] = a.st[p0 + w*64 + pp*16 + c15];
  size_t obase = ((size_t)(b - a.b0)*a.Cd + dstOff)*HW + hwb + w*64;
  #pragma unroll
  for (int po=0;po<4;po++)
    #pragma unroll
    for (int j=0;j<4;j++){
      int oc = po*16 + g*4 + j;
      float Ao = a.Af[o0+oc], Bo = a.Bf[o0+oc];
      u16* dp = a.dst + obase + (size_t)oc*HW + c15;
      #pragma unroll
      for (int pp=0;pp<4;pp++)
        dp[pp*16] = f2bf(stv[pp].y*(acc[pp][po][j] - stv[pp].x*Ao) + Bo);
    }
}

// ================= DFFN pi-GEMM with fused spectral circular conv =================
// block = 8x32 spatial tile (4 patches) x 64 out-ch; grid (256 tiles, 4 ch-groups, 2 b)
__global__ __launch_bounds__(256) void k_gemm_pi(
    const float* __restrict__ src, const float2* __restrict__ st,
    const u16* __restrict__ Wf, const float* __restrict__ Af, const float* __restrict__ Bf,
    const float* __restrict__ G, u16* __restrict__ Y0, int b0)
{
  __shared__ char smU[256*66*2];   // union: lsX (32KB) / yd u16[256][66] (33KB)
  __shared__ uint4 lsW[64*8];      // 8KB
  __shared__ float gs[64*65];      // 16.6KB
  uint4* lsX = (uint4*)smU;
  u16*   yd  = (u16*)smU;
  int tid = threadIdx.x;
  int tile = blockIdx.x;
  int h0 = (tile>>3)*8, w0 = (tile&7)*32;
  int o0 = blockIdx.y*64;
  int bl = blockIdx.z;
  int b = b0 + bl;
  // stage g (channel group o0..o0+63), padded stride 65
  #pragma unroll
  for (int i=0;i<16;i++){
    int idx = i*256 + tid;
    gs[(idx>>6)*65 + (idx&63)] = G[(size_t)o0*64 + idx];
  }
  // stage W'
  {
    const uint4* wsrc = (const uint4*)(Wf + (size_t)o0*64);
    #pragma unroll
    for (int i=0;i<2;i++){
      int idx = i*256 + tid, row = idx>>3, s = idx&7;
      lsW[row*8 + (s ^ (row&7))] = wsrc[idx];
    }
  }
  // stage X: spatial tile, px p = tid -> (r,c)=(p>>5, p&31)
  {
    int hw = (h0 + (tid>>5))*256 + w0 + (tid&31);
    const float* sp = src + (size_t)b*64*HW + hw;
    uint4* xrow = lsX + tid*8;
    #pragma unroll
    for (int sl=0; sl<8; sl++){
      float e0=sp[(size_t)(sl*8+0)*HW], e1=sp[(size_t)(sl*8+1)*HW];
      float e2=sp[(size_t)(sl*8+2)*HW], e3=sp[(size_t)(sl*8+3)*HW];
      float e4=sp[(size_t)(sl*8+4)*HW], e5=sp[(size_t)(sl*8+5)*HW];
      float e6=sp[(size_t)(sl*8+6)*HW], e7=sp[(size_t)(sl*8+7)*HW];
      uint4 pkv; pkv.x=pk2(e0,e1); pkv.y=pk2(e2,e3); pkv.z=pk2(e4,e5); pkv.w=pk2(e6,e7);
      xrow[sl ^ (tid&7)] = pkv;
    }
  }
  __syncthreads();
  int w = tid>>6, l = tid&63, g2 = l>>4, c15 = l&15;
  f32x4 acc[4][4];
  #pragma unroll
  for (int pp=0;pp<4;pp++)
    #pragma unroll
    for (int po=0;po<4;po++) acc[pp][po] = (f32x4){0.f,0.f,0.f,0.f};
  #pragma unroll
  for (int kk=0; kk<2; kk++){
    v8s wf[4], xf[4];
    #pragma unroll
    for (int po=0;po<4;po++){ int row = po*16 + c15; wf[po] = as8(lsW[row*8 + ((kk*4+g2) ^ (row&7))]); }
    #pragma unroll
    for (int pp=0;pp<4;pp++){ int row = w*64 + pp*16 + c15; xf[pp] = as8(lsX[row*8 + ((kk*4+g2) ^ (row&7))]); }
    #pragma unroll
    for (int pp=0;pp<4;pp++)
      #pragma unroll
      for (int po=0;po<4;po++)
        acc[pp][po] = __builtin_amdgcn_mfma_f32_16x16x32_bf16(wf[po], xf[pp], acc[pp][po], 0,0,0);
  }
  // per-px stats
  float2 stv[4];
  #pragma unroll
  for (int pp=0;pp<4;pp++){
    int n = w*64 + pp*16 + c15;
    int hw = (h0 + (n>>5))*256 + w0 + (n&31);
    stv[pp] = st[(size_t)b*HW + hw];
  }
  __syncthreads();   // all lsX reads done; smU becomes yd
  // LN-fold -> yd[n][oc], stride 66
  #pragma unroll
  for (int po=0;po<4;po++)
    #pragma unroll
    for (int j=0;j<4;j++){
      int oc = po*16 + g2*4 + j;
      float Ao = Af[o0+oc], Bo = Bf[o0+oc];
      #pragma unroll
      for (int pp=0;pp<4;pp++){
        int n = w*64 + pp*16 + c15;
        yd[n*66 + oc] = f2bf(stv[pp].y*(acc[pp][po][j] - stv[pp].x*Ao) + Bo);
      }
    }
  __syncthreads();
  // circular conv: thread = (pch 0..3, ch 0..63)
  int pch = tid & 3, ch = tid >> 2;
  float gr[64];
  #pragma unroll
  for (int t2=0;t2<64;t2++) gr[t2] = gs[ch*65 + t2];
  float o[8][8];
  #pragma unroll
  for (int i=0;i<8;i++)
    #pragma unroll
    for (int j=0;j<8;j++) o[i][j] = 0.f;
  #pragma unroll
  for (int u=0;u<8;u++){
    float qv[8];
    #pragma unroll
    for (int v=0;v<8;v++) qv[v] = bf2f(yd[(u*32 + pch*8 + v)*66 + ch]);
    #pragma unroll
    for (int v=0;v<8;v++){
      float qq = qv[v];
      #pragma unroll
      for (int i=0;i<8;i++){
        const int grb = ((i-u)&7)*8;
        #pragma unroll
        for (int j=0;j<8;j++) o[i][j] += qq * gr[grb + ((j-v)&7)];
      }
    }
  }
  u16* op = Y0 + ((size_t)(bl*256 + o0 + ch))*HW + (size_t)h0*256 + w0 + pch*8;
  #pragma unroll
  for (int i=0;i<8;i++){
    uint4 pkv;
    pkv.x = pk2(o[i][0],o[i][1]); pkv.y = pk2(o[i][2],o[i][3]);
    pkv.z = pk2(o[i][4],o[i][5]); pkv.w = pk2(o[i][6],o[i][7]);
    *(uint4*)(op + (size_t)i*256) = pkv;
  }
}

// ================= attn epilogue GEMM (K=128): out = x + Wpo * (v .* LN128(oraw)) =================
__global__ __launch_bounds__(256) void k_gemm_attn(
    const float* __restrict__ x, const u16* __restrict__ oraw, const u16* __restrict__ vb,
    const float* __restrict__ lnw, const float* __restrict__ lnb,
    const u16* __restrict__ Wf, float* __restrict__ out)
{
  __shared__ uint4 lsX[128*16];  // 32KB
  __shared__ uint4 lsW[64*16];   // 16KB
  __shared__ float2 sPart[256];
  __shared__ float2 sStat[128];
  int tid = threadIdx.x;
  int p0 = blockIdx.x*128;
  int b = p0 >> 16, hwb = p0 & 65535;
  int px = tid & 127, hf = tid >> 7;
  {
    const uint4* wsrc = (const uint4*)Wf;
    #pragma unroll
    for (int i=0;i<4;i++){
      int idx = i*256 + tid, row = idx>>4, s = idx&15;
      lsW[row*16 + (s ^ (row&15))] = wsrc[idx];
    }
  }
  const u16* op_ = oraw + ((size_t)b*128 + hf*64)*HW + hwb + px;
  float sum = 0.f, ssq = 0.f;
  #pragma unroll
  for (int sl=0; sl<8; sl++){
    u32 wds[4];
    #pragma unroll
    for (int q2=0;q2<4;q2++){
      u16 lo = op_[(size_t)(sl*8+q2*2  )*HW];
      u16 hi = op_[(size_t)(sl*8+q2*2+1)*HW];
      float fl = bf2f(lo), fh = bf2f(hi);
      sum += fl + fh; ssq += fl*fl + fh*fh;
      wds[q2] = (u32)lo | ((u32)hi << 16);
    }
    int s = hf*8 + sl;
    lsX[px*16 + (s ^ (px&15))] = make_uint4(wds[0],wds[1],wds[2],wds[3]);
  }
  sPart[tid] = make_float2(sum, ssq);
  __syncthreads();
  if (tid < 128){
    float2 A = sPart[tid], B = sPart[tid+128];
    float s = A.x + B.x, q = A.y + B.y;
    float mu = s*(1.f/128.f);
    float var = q*(1.f/128.f) - mu*mu;
    sStat[tid] = make_float2(mu, rsqrtf(fmaxf(var,0.f)+1e-5f));
  }
  __syncthreads();
  float2 st = sStat[px];
  const u16* vp = vb + ((size_t)b*128 + hf*64)*HW + hwb + px;
  #pragma unroll
  for (int sl=0; sl<8; sl++){
    int s = hf*8 + sl;
    int li = px*16 + (s ^ (px&15));
    uint4 raw = lsX[li];
    u32 wds[4] = {raw.x, raw.y, raw.z, raw.w};
    u32 ow[4];
    #pragma unroll
    for (int q2=0;q2<4;q2++){
      int ch = hf*64 + sl*8 + q2*2;
      float e0 = bf2f((u16)(wds[q2]&0xffff)), e1 = bf2f((u16)(wds[q2]>>16));
      float v0 = bf2f(vp[(size_t)(sl*8+q2*2  )*HW]);
      float v1 = bf2f(vp[(size_t)(sl*8+q2*2+1)*HW]);
      float r0 = ((e0-st.x)*st.y*lnw[ch  ] + lnb[ch  ])*v0;
      float r1 = ((e1-st.x)*st.y*lnw[ch+1] + lnb[ch+1])*v1;
      ow[q2] = pk2(r0, r1);
    }
    lsX[li] = make_uint4(ow[0],ow[1],ow[2],ow[3]);
  }
  __syncthreads();
  int w4 = tid>>6, l = tid&63, g = l>>4, c15 = l&15;
  f32x4 acc[2][4];
  #pragma unroll
  for (int pp=0;pp<2;pp++)
    #pragma unroll
    for (int po=0;po<4;po++) acc[pp][po] = (f32x4){0.f,0.f,0.f,0.f};
  #pragma unroll
  for (int kk=0; kk<4; kk++){
    v8s wf[4], xf[2];
    #pragma unroll
    for (int po=0;po<4;po++){ int row = po*16 + c15; wf[po] = as8(lsW[row*16 + ((kk*4+g) ^ (row&15))]); }
    #pragma unroll
    for (int pp=0;pp<2;pp++){ int row = w4*32 + pp*16 + c15; xf[pp] = as8(lsX[row*16 + ((kk*4+g) ^ (row&15))]); }
    #pragma unroll
    for (int pp=0;pp<2;pp++)
      #pragma unroll
      for (int po=0;po<4;po++)
        acc[pp][po] = __builtin_amdgcn_mfma_f32_16x16x32_bf16(wf[po], xf[pp], acc[pp][po], 0,0,0);
  }
  size_t obase = (size_t)b*64*HW + hwb + w4*32;
  #pragma unroll
  for (int po=0;po<4;po++)
    #pragma unroll
    for (int j=0;j<4;j++){
      int oc = po*16 + g*4 + j;
      const float* xs = x + obase + (size_t)oc*HW + c15;
      float* dp = out + obase + (size_t)oc*HW + c15;
      #pragma unroll
      for (int pp=0;pp<2;pp++) dp[pp*16] = xs[pp*16] + acc[pp][po][j];
    }
}

// ================= ffn epilogue GEMM (K=128): out += Wpo * y3g (pre-gated) =================
__global__ __launch_bounds__(256) void k_gemm_ffn(
    const u16* __restrict__ y3g, const u16* __restrict__ Wf, float* __restrict__ out,
    int pxbase, int b0)
{
  __shared__ uint4 lsX[128*16];
  __shared__ uint4 lsW[64*16];
  int tid = threadIdx.x;
  int p0 = pxbase + blockIdx.x*128;
  int b = p0 >> 16, hwb = p0 & 65535;
  int px = tid & 127, hf = tid >> 7;
  {
    const uint4* wsrc = (const uint4*)Wf;
    #pragma unroll
    for (int i=0;i<4;i++){
      int idx = i*256 + tid, row = idx>>4, s = idx&15;
      lsW[row*16 + (s ^ (row&15))] = wsrc[idx];
    }
  }
  const u16* yp = y3g + ((size_t)(b-b0)*128 + hf*64)*HW + hwb + px;
  #pragma unroll
  for (int sl=0; sl<8; sl++){
    u32 wds[4];
    #pragma unroll
    for (int q2=0;q2<4;q2++){
      u16 lo = yp[(size_t)(sl*8+q2*2  )*HW];
      u16 hi = yp[(size_t)(sl*8+q2*2+1)*HW];
      wds[q2] = (u32)lo | ((u32)hi << 16);
    }
    int s = hf*8 + sl;
    lsX[px*16 + (s ^ (px&15))] = make_uint4(wds[0],wds[1],wds[2],wds[3]);
  }
  __syncthreads();
  int w4 = tid>>6, l = tid&63, g = l>>4, c15 = l&15;
  f32x4 acc[2][4];
  #pragma unroll
  for (int pp=0;pp<2;pp++)
    #pragma unroll
    for (int po=0;po<4;po++) acc[pp][po] = (f32x4){0.f,0.f,0.f,0.f};
  #pragma unroll
  for (int kk=0; kk<4; kk++){
    v8s wf[4], xf[2];
    #pragma unroll
    for (int po=0;po<4;po++){ int row = po*16 + c15; wf[po] = as8(lsW[row*16 + ((kk*4+g) ^ (row&15))]); }
    #pragma unroll
    for (int pp=0;pp<2;pp++){ int row = w4*32 + pp*16 + c15; xf[pp] = as8(lsX[row*16 + ((kk*4+g) ^ (row&15))]); }
    #pragma unroll
    for (int pp=0;pp<2;pp++)
      #pragma unroll
      for (int po=0;po<4;po++)
        acc[pp][po] = __builtin_amdgcn_mfma_f32_16x16x32_bf16(wf[po], xf[pp], acc[pp][po], 0,0,0);
  }
  size_t obase = (size_t)b*64*HW + hwb + w4*32;
  #pragma unroll
  for (int po=0;po<4;po++)
    #pragma unroll
    for (int j=0;j<4;j++){
      int oc = po*16 + g*4 + j;
      float* dp = out + obase + (size_t)oc*HW + c15;
      #pragma unroll
      for (int pp=0;pp<2;pp++) dp[pp*16] = dp[pp*16] + acc[pp][po][j];
    }
}

// ================= dw3x3 row-of-8 accumulate helper =================
__device__ __forceinline__ void dw8_acc(const u16* __restrict__ sp, const float* __restrict__ w9,
                                        int h, int w8, float acc[8])
{
  #pragma unroll
  for (int r=0;r<3;r++){
    int hh = h + r - 1;
    if (hh < 0 || hh > 255) continue;
    const u16* rp = sp + hh*256 + w8;
    uint4 u = *(const uint4*)rp;
    float vm[10];
    vm[0] = (w8 > 0) ? bf2f(rp[-1]) : 0.f;
    vm[1]=bf2f((u16)(u.x&0xffff)); vm[2]=bf2f((u16)(u.x>>16));
    vm[3]=bf2f((u16)(u.y&0xffff)); vm[4]=bf2f((u16)(u.y>>16));
    vm[5]=bf2f((u16)(u.z&0xffff)); vm[6]=bf2f((u16)(u.z>>16));
    vm[7]=bf2f((u16)(u.w&0xffff)); vm[8]=bf2f((u16)(u.w>>16));
    vm[9] = (w8 < 248) ? bf2f(rp[8]) : 0.f;
    float wa = w9[r*3], wb = w9[r*3+1], wc = w9[r*3+2];
    #pragma unroll
    for (int j=0;j<8;j++) acc[j] += vm[j]*wa + vm[j+1]*wb + vm[j+2]*wc;
  }
}

// ================= depthwise 3x3, 8px/thread (attention v branch) =================
__global__ __launch_bounds__(256) void k_dw8(
    const u16* __restrict__ src, const float* __restrict__ wgt, int c0,
    u16* __restrict__ dst, int cmask, int lg, int dstCd, int dstOff)
{
  int t = blockIdx.x*256 + threadIdx.x;
  int w8 = (t & 31)*8, h = (t>>5) & 255;
  int plane = t >> 13;
  int c = plane & cmask, b = plane >> lg;
  const u16* sp = src + (size_t)plane*HW;
  float acc[8] = {0,0,0,0,0,0,0,0};
  dw8_acc(sp, wgt + (size_t)(c0+c)*9, h, w8, acc);
  uint4 pkv;
  pkv.x = pk2(acc[0],acc[1]); pkv.y = pk2(acc[2],acc[3]);
  pkv.z = pk2(acc[4],acc[5]); pkv.w = pk2(acc[6],acc[7]);
  *(uint4*)(dst + ((size_t)(b*dstCd + dstOff + c))*HW + h*256 + w8) = pkv;
}

// ================= DFFN: dw3x3 on ch c and c+128 + GELU gate -> 128-ch Y3g =================
__global__ __launch_bounds__(256) void k_dw8g(
    const u16* __restrict__ Y0, const float* __restrict__ wgt, u16* __restrict__ Y3g)
{
  int t = blockIdx.x*256 + threadIdx.x;
  int w8 = (t & 31)*8, h = (t>>5) & 255;
  int pc = t >> 13;                 // 0..255
  int c = pc & 127, bl = pc >> 7;
  const u16* spA = Y0 + ((size_t)(bl*256 + c      ))*HW;
  const u16* spG = Y0 + ((size_t)(bl*256 + 128 + c))*HW;
  float aA[8] = {0,0,0,0,0,0,0,0};
  float aG[8] = {0,0,0,0,0,0,0,0};
  dw8_acc(spA, wgt + (size_t)c*9,       h, w8, aA);
  dw8_acc(spG, wgt + (size_t)(128+c)*9, h, w8, aG);
  float r[8];
  #pragma unroll
  for (int j=0;j<8;j++) r[j] = gelu_exact(aA[j]) * aG[j];
  uint4 pkv;
  pkv.x = pk2(r[0],r[1]); pkv.y = pk2(r[2],r[3]);
  pkv.z = pk2(r[4],r[5]); pkv.w = pk2(r[6],r[7]);
  *(uint4*)(Y3g + ((size_t)(bl*128 + c))*HW + h*256 + w8) = pkv;
}

// ================= dw3x3 of one row-of-8 to LDS (attention q/k path) =================
__device__ __forceinline__ void dw_row8_lds(const u16* __restrict__ plane, const float* __restrict__ w9,
                                            int h, int w8, float* __restrict__ dstLds)
{
  float acc[8] = {0,0,0,0,0,0,0,0};
  dw8_acc(plane, w9, h, w8, acc);
  #pragma unroll
  for (int j=0;j<8;j++) dstLds[j] = acc[j];
}

// ================= fused dw(q), dw(k) + per-patch 8x8 circular conv, LDS-staged =================
__global__ __launch_bounds__(256) void k_circqk2(
    const u16* __restrict__ bq, const u16* __restrict__ bk,
    const float* __restrict__ dwq, const float* __restrict__ dwk, int c0,
    u16* __restrict__ oraw, int oc0)
{
  __shared__ float qd[8][288];   // [row][patch*9 + v]
  __shared__ float kd[8][288];
  int tid = threadIdx.x;
  int p = tid & 31, i = tid >> 5;
  int c = blockIdx.y, b = blockIdx.z;
  int h0 = blockIdx.x*8;
  const u16* qp = bq + ((size_t)(b*64+c))*HW;
  const u16* kp = bk + ((size_t)(b*64+c))*HW;
  dw_row8_lds(qp, dwq + (size_t)(c0+c)*9, h0+i, p*8, &qd[i][p*9]);
  dw_row8_lds(kp, dwk + (size_t)(c0+c)*9, h0+i, p*8, &kd[i][p*9]);
  __syncthreads();
  float o[8] = {0,0,0,0,0,0,0,0};
  #pragma unroll
  for (int u=0;u<8;u++){
    float qv[8], kr[8];
    #pragma unroll
    for (int v=0;v<8;v++) qv[v] = qd[u][p*9+v];
    const float* krow = &kd[(i-u)&7][p*9];
    #pragma unroll
    for (int e=0;e<8;e++) kr[e] = krow[e];
    #pragma unroll
    for (int v=0;v<8;v++){
      float qq = qv[v];
      #pragma unroll
      for (int j=0;j<8;j++) o[j] += qq * kr[(j-v)&7];
    }
  }
  u16* op = oraw + ((size_t)(b*128 + oc0 + c))*HW + (size_t)(h0+i)*256 + p*8;
  uint4 pkv;
  pkv.x = pk2(o[0],o[1]); pkv.y = pk2(o[2],o[3]);
  pkv.z = pk2(o[4],o[5]); pkv.w = pk2(o[6],o[7]);
  *(uint4*)op = pkv;
}

extern "C" void kernel_launch(void* const* d_in, const int* in_sizes, int n_in,
                              void* d_out, int out_size, void* d_ws, size_t ws_size,
                              hipStream_t stream)
{
  const float* x       = (const float*)d_in[0];
  const float* evt     = (const float*)d_in[1];
  const float* ln1i_w  = (const float*)d_in[2];
  const float* ln1i_b  = (const float*)d_in[3];
  const float* ln1e_w  = (const float*)d_in[4];
  const float* ln1e_b  = (const float*)d_in[5];
  const float* w_q     = (const float*)d_in[6];
  const float* dw_q    = (const float*)d_in[7];
  const float* w_kv    = (const float*)d_in[8];
  const float* dw_kv   = (const float*)d_in[9];
  const float* lnA_w   = (const float*)d_in[10];
  const float* lnA_b   = (const float*)d_in[11];
  const float* w_po_at = (const float*)d_in[12];
  const float* ln2_w   = (const float*)d_in[13];
  const float* ln2_b   = (const float*)d_in[14];
  const float* w_pi    = (const float*)d_in[15];
  const float* fft_par = (const float*)d_in[16];
  const float* dw_ffn  = (const float*)d_in[17];
  const float* w_poffn = (const float*)d_in[18];
  float* out = (float*)d_out;

  char* ws = (char*)d_ws;
  const size_t MiB = 1048576ull;
  u16*   P1   = (u16*)(ws);                    // 32 MiB  (B,64,HW)
  u16*   ORAW = (u16*)(ws + 32*MiB);           // 64 MiB  (B,128,HW)
  u16*   P2   = (u16*)(ws + 96*MiB);           // 32 MiB
  u16*   VBUF = (u16*)(ws + 96*MiB);           // 64 MiB  (B,128,HW) — after P2 dead
  float2* SX  = (float2*)(ws + 144*MiB);       // 2 MiB
  float2* SE  = (float2*)(ws + 146*MiB);       // 2 MiB
  float2* S2  = (float2*)(ws);                 // 2 MiB — after P1 dead
  u16*   Y0   = (u16*)(ws + 8*MiB);            // 64 MiB  (2,256,HW) half
  u16*   Y3G  = (u16*)(ws + 72*MiB);           // 32 MiB  (2,128,HW) half (gated)
  char* sm = ws + 160*MiB;
  float* G    = (float*)(sm);                  // 64 KiB
  u16* WQF    = (u16*)(sm + 65536);
  u16* WKVF   = (u16*)(sm + 81920);
  u16* WPIF   = (u16*)(sm + 114688);
  u16* WPAF   = (u16*)(sm + 147456);
  u16* WPFF   = (u16*)(sm + 163840);
  float* AQ   = (float*)(sm + 180224);
  float* BQ   = (float*)(sm + 180736);
  float* AKV  = (float*)(sm + 181248);
  float* BKV  = (float*)(sm + 182272);
  float* API  = (float*)(sm + 183296);
  float* BPI  = (float*)(sm + 184320);

  dim3 blk256(256);

  k_prep<<<69, blk256, 0, stream>>>(fft_par, G,
      w_q, ln1i_w, ln1i_b, WQF, AQ, BQ,
      w_kv, ln1e_w, ln1e_b, WKVF, AKV, BKV,
      w_pi, ln2_w, ln2_b, WPIF, API, BPI,
      w_po_at, WPAF, w_poffn, WPFF);

  k_stats<<<dim3(1024,2), blk256, 0, stream>>>(x, SX, evt, SE);

  // ---- attention q,k chunks ----
  for (int i=0;i<2;i++){
    GA qa = {x,   SX, WQF,  AQ,  BQ,  P1, 64*i, 0, 64, 0, 0};
    GA ka = {evt, SE, WKVF, AKV, BKV, P2, 64*i, 0, 64, 0, 0};
    k_gemm64<<<dim3(1024,2,1), blk256, 0, stream>>>(qa, ka);
    k_circqk2<<<dim3(32,64,4), blk256, 0, stream>>>(P1, P2, dw_q, dw_kv, 64*i, ORAW, 64*i);
  }
  // ---- v chunks ----
  for (int i=0;i<2;i++){
    GA va = {evt, SE, WKVF, AKV, BKV, P1, 128+64*i, 0, 64, 0, 0};
    k_gemm64<<<dim3(1024,1,1), blk256, 0, stream>>>(va, va);
    k_dw8<<<8192, blk256, 0, stream>>>(P1, dw_kv, 128+64*i, VBUF, 63, 6, 128, 64*i);
  }
  // ---- attn epilogue -> d_out ----
  k_gemm_attn<<<2048, blk256, 0, stream>>>(x, ORAW, VBUF, lnA_w, lnA_b, WPAF, out);

  // ---- ln2 stats on x2 ----
  k_stats<<<dim3(1024,1), blk256, 0, stream>>>(out, S2, out, S2);

  // ---- DFFN in two batch-halves: pi-GEMM(+circ) -> dw+gate -> ffn-GEMM ----
  for (int h=0;h<2;h++){
    k_gemm_pi<<<dim3(256,4,2), blk256, 0, stream>>>(out, S2, WPIF, API, BPI, G, Y0, 2*h);
    k_dw8g<<<8192, blk256, 0, stream>>>(Y0, dw_ffn, Y3G);
    k_gemm_ffn<<<1024, blk256, 0, stream>>>(Y3G, WPFF, out, h*131072, 2*h);
  }
}

// Round 7
// 624.156 us; speedup vs baseline: 1.4703x; 1.4703x over previous
//
#include <hip/hip_runtime.h>

#define HW 65536          // 256*256
#define NPOS 262144       // B(4) * HW

typedef unsigned int   u32;
typedef unsigned short u16;
typedef __attribute__((ext_vector_type(8))) short v8s;
typedef __attribute__((ext_vector_type(4))) float f32x4;

__device__ __forceinline__ float bf2f(u16 h){
  union { u32 u; float f; } c; c.u = ((u32)h) << 16; return c.f;
}
__device__ __forceinline__ u16 f2bf(float f){
  union { u32 u; float f; } c; c.f = f;
  u32 r = c.u + 0x7fffu + ((c.u >> 16) & 1u);
  return (u16)(r >> 16);
}
__device__ __forceinline__ u32 pk2(float a, float b){
  return (u32)f2bf(a) | ((u32)f2bf(b) << 16);
}
__device__ __forceinline__ v8s as8(uint4 u){
  union { uint4 a; v8s b; } c; c.a = u; return c.b;
}
__device__ __forceinline__ float gelu_exact(float x){
  return 0.5f*x*(1.0f+erff(x*0.70710678118654752f));
}

// ================= prep: spectral kernel g + LN-folded bf16 weights =================
__device__ void fold_w(const float* __restrict__ W, int rows,
                       const float* __restrict__ lw, const float* __restrict__ lb,
                       u16* __restrict__ Wf, float* __restrict__ A, float* __restrict__ B){
  int tid = threadIdx.x;
  for (int e = tid; e < rows*64; e += 256) Wf[e] = f2bf(lw[e & 63] * W[e]);
  for (int r = tid; r < rows; r += 256){
    float a = 0.f, b2 = 0.f;
    for (int c = 0; c < 64; c++){ float w = W[r*64+c]; a += lw[c]*w; b2 += lb[c]*w; }
    A[r] = a; B[r] = b2;
  }
}

__global__ void k_prep(const float* __restrict__ M, float* __restrict__ g,
    const float* wq,  const float* l1iw, const float* l1ib, u16* wqf,  float* aq,  float* bq,
    const float* wkv, const float* l1ew, const float* l1eb, u16* wkvf, float* akv, float* bkv,
    const float* wpi, const float* l2w,  const float* l2b,  u16* wpif, float* api, float* bpi,
    const float* wpa, u16* wpaf, const float* wpf, u16* wpff)
{
  int blk = blockIdx.x, tid = threadIdx.x;
  if (blk < 64){
    int t = blk*256 + tid;           // < 256*64
    int c = t >> 6, uv = t & 63, u = uv >> 3, v = uv & 7;
    const float* mc = M + c*40;
    const float ctab[8] = {1.f, 0.70710678118654752f, 0.f, -0.70710678118654752f,
                           -1.f, -0.70710678118654752f, 0.f, 0.70710678118654752f};
    float acc = 0.f;
    for (int k1=0;k1<8;k1++)
      for (int k2=0;k2<8;k2++){
        float s = (k2<=4) ? mc[k1*5+k2] : mc[(((8-k1)&7)*5) + (8-k2)];
        acc += s * ctab[(k1*u + k2*v)&7];
      }
    g[t] = acc * (1.f/64.f);
  } else if (blk == 64){ fold_w(wq, 128, l1iw, l1ib, wqf, aq, bq); }
  else if (blk == 65){ fold_w(wkv, 256, l1ew, l1eb, wkvf, akv, bkv); }
  else if (blk == 66){ fold_w(wpi, 256, l2w, l2b, wpif, api, bpi); }
  else if (blk == 67){ for (int e=tid; e<64*128; e+=256) wpaf[e] = f2bf(wpa[e]); }
  else               { for (int e=tid; e<64*128; e+=256) wpff[e] = f2bf(wpf[e]); }
}

// ========== K=64 GEMM, LN folded into weights, per-pixel stats computed inline ==========
// dst[dstOff+z*64+o] = inv*(acc - mu*A) + B for z in [0,nz)
struct GA {
  const float* src; const u16* Wf; const float* Af; const float* Bf;
  u16* dst; int o0; int dstOff; int Cd; int b0; int pxbase; int nz;
};

__global__ __launch_bounds__(256) void k_gemm64(GA a0, GA a1){
  GA a = (blockIdx.y == 0) ? a0 : a1;
  __shared__ uint4 lsX[256*8];    // 32KB
  __shared__ uint4 lsW[256*8];    // 32KB (up to 256 weight rows)
  __shared__ float2 sStat[256];   // 2KB per-pixel (mu, inv)
  int tid = threadIdx.x;
  int p0 = a.pxbase + blockIdx.x*256;
  int b = p0 >> 16, hwb = p0 & 65535;
  // stage W' rows [o0, o0+64*nz)
  {
    const uint4* wsrc = (const uint4*)(a.Wf + (size_t)a.o0*64);
    for (int i=0; i<a.nz*2; i++){
      int idx = i*256 + tid, row = idx>>3, s = idx&7;
      lsW[row*8 + (s ^ (row&7))] = wsrc[idx];
    }
  }
  // stage X (bf16) + inline LN stats
  {
    const float* sp = a.src + (size_t)b*64*HW + hwb + tid;
    uint4* xrow = lsX + tid*8;
    float sm = 0.f, sq = 0.f;
    #pragma unroll
    for (int sl=0; sl<8; sl++){
      float e[8];
      #pragma unroll
      for (int j=0;j<8;j++){ e[j] = sp[(size_t)(sl*8+j)*HW]; sm += e[j]; sq += e[j]*e[j]; }
      uint4 pkv; pkv.x=pk2(e[0],e[1]); pkv.y=pk2(e[2],e[3]);
      pkv.z=pk2(e[4],e[5]); pkv.w=pk2(e[6],e[7]);
      xrow[sl ^ (tid&7)] = pkv;
    }
    float mu = sm*(1.f/64.f);
    float var = sq*(1.f/64.f) - mu*mu;
    sStat[tid] = make_float2(mu, rsqrtf(fmaxf(var,0.f)+1e-5f));
  }
  __syncthreads();
  int w = tid>>6, l = tid&63, g = l>>4, c15 = l&15;
  float2 stv[4];
  #pragma unroll
  for (int pp=0;pp<4;pp++) stv[pp] = sStat[w*64 + pp*16 + c15];

  for (int z=0; z<a.nz; z++){
    f32x4 acc[4][4];
    #pragma unroll
    for (int pp=0;pp<4;pp++)
      #pragma unroll
      for (int po=0;po<4;po++) acc[pp][po] = (f32x4){0.f,0.f,0.f,0.f};
    #pragma unroll
    for (int kk=0; kk<2; kk++){
      v8s wf[4], xf[4];
      #pragma unroll
      for (int po=0;po<4;po++){ int row = z*64 + po*16 + c15; wf[po] = as8(lsW[row*8 + ((kk*4+g) ^ (row&7))]); }
      #pragma unroll
      for (int pp=0;pp<4;pp++){ int row = w*64 + pp*16 + c15; xf[pp] = as8(lsX[row*8 + ((kk*4+g) ^ (row&7))]); }
      #pragma unroll
      for (int pp=0;pp<4;pp++)
        #pragma unroll
        for (int po=0;po<4;po++)
          acc[pp][po] = __builtin_amdgcn_mfma_f32_16x16x32_bf16(wf[po], xf[pp], acc[pp][po], 0,0,0);
    }
    size_t obase = ((size_t)(b - a.b0)*a.Cd + a.dstOff + z*64)*HW + hwb + w*64;
    #pragma unroll
    for (int po=0;po<4;po++)
      #pragma unroll
      for (int j=0;j<4;j++){
        int oc = po*16 + g*4 + j;
        float Ao = a.Af[a.o0 + z*64 + oc], Bo = a.Bf[a.o0 + z*64 + oc];
        u16* dp = a.dst + obase + (size_t)oc*HW + c15;
        #pragma unroll
        for (int pp=0;pp<4;pp++)
          dp[pp*16] = f2bf(stv[pp].y*(acc[pp][po][j] - stv[pp].x*Ao) + Bo);
      }
  }
}

// ================= attn epilogue GEMM (K=128): out = x + Wpo * (v .* LN128(oraw)) =================
__global__ __launch_bounds__(256) void k_gemm_attn(
    const float* __restrict__ x, const u16* __restrict__ oraw, const u16* __restrict__ vb,
    const float* __restrict__ lnw, const float* __restrict__ lnb,
    const u16* __restrict__ Wf, float* __restrict__ out)
{
  __shared__ uint4 lsX[128*16];  // 32KB
  __shared__ uint4 lsW[64*16];   // 16KB
  __shared__ float2 sPart[256];
  __shared__ float2 sStat[128];
  int tid = threadIdx.x;
  int p0 = blockIdx.x*128;
  int b = p0 >> 16, hwb = p0 & 65535;
  int px = tid & 127, hf = tid >> 7;
  {
    const uint4* wsrc = (const uint4*)Wf;
    #pragma unroll
    for (int i=0;i<4;i++){
      int idx = i*256 + tid, row = idx>>4, s = idx&15;
      lsW[row*16 + (s ^ (row&15))] = wsrc[idx];
    }
  }
  const u16* op_ = oraw + ((size_t)b*128 + hf*64)*HW + hwb + px;
  float sum = 0.f, ssq = 0.f;
  #pragma unroll
  for (int sl=0; sl<8; sl++){
    u32 wds[4];
    #pragma unroll
    for (int q2=0;q2<4;q2++){
      u16 lo = op_[(size_t)(sl*8+q2*2  )*HW];
      u16 hi = op_[(size_t)(sl*8+q2*2+1)*HW];
      float fl = bf2f(lo), fh = bf2f(hi);
      sum += fl + fh; ssq += fl*fl + fh*fh;
      wds[q2] = (u32)lo | ((u32)hi << 16);
    }
    int s = hf*8 + sl;
    lsX[px*16 + (s ^ (px&15))] = make_uint4(wds[0],wds[1],wds[2],wds[3]);
  }
  sPart[tid] = make_float2(sum, ssq);
  __syncthreads();
  if (tid < 128){
    float2 A = sPart[tid], B = sPart[tid+128];
    float s = A.x + B.x, q = A.y + B.y;
    float mu = s*(1.f/128.f);
    float var = q*(1.f/128.f) - mu*mu;
    sStat[tid] = make_float2(mu, rsqrtf(fmaxf(var,0.f)+1e-5f));
  }
  __syncthreads();
  float2 st = sStat[px];
  const u16* vp = vb + ((size_t)b*128 + hf*64)*HW + hwb + px;
  #pragma unroll
  for (int sl=0; sl<8; sl++){
    int s = hf*8 + sl;
    int li = px*16 + (s ^ (px&15));
    uint4 raw = lsX[li];
    u32 wds[4] = {raw.x, raw.y, raw.z, raw.w};
    u32 ow[4];
    #pragma unroll
    for (int q2=0;q2<4;q2++){
      int ch = hf*64 + sl*8 + q2*2;
      float e0 = bf2f((u16)(wds[q2]&0xffff)), e1 = bf2f((u16)(wds[q2]>>16));
      float v0 = bf2f(vp[(size_t)(sl*8+q2*2  )*HW]);
      float v1 = bf2f(vp[(size_t)(sl*8+q2*2+1)*HW]);
      float r0 = ((e0-st.x)*st.y*lnw[ch  ] + lnb[ch  ])*v0;
      float r1 = ((e1-st.x)*st.y*lnw[ch+1] + lnb[ch+1])*v1;
      ow[q2] = pk2(r0, r1);
    }
    lsX[li] = make_uint4(ow[0],ow[1],ow[2],ow[3]);
  }
  __syncthreads();
  int w4 = tid>>6, l = tid&63, g = l>>4, c15 = l&15;
  f32x4 acc[2][4];
  #pragma unroll
  for (int pp=0;pp<2;pp++)
    #pragma unroll
    for (int po=0;po<4;po++) acc[pp][po] = (f32x4){0.f,0.f,0.f,0.f};
  #pragma unroll
  for (int kk=0; kk<4; kk++){
    v8s wf[4], xf[2];
    #pragma unroll
    for (int po=0;po<4;po++){ int row = po*16 + c15; wf[po] = as8(lsW[row*16 + ((kk*4+g) ^ (row&15))]); }
    #pragma unroll
    for (int pp=0;pp<2;pp++){ int row = w4*32 + pp*16 + c15; xf[pp] = as8(lsX[row*16 + ((kk*4+g) ^ (row&15))]); }
    #pragma unroll
    for (int pp=0;pp<2;pp++)
      #pragma unroll
      for (int po=0;po<4;po++)
        acc[pp][po] = __builtin_amdgcn_mfma_f32_16x16x32_bf16(wf[po], xf[pp], acc[pp][po], 0,0,0);
  }
  size_t obase = (size_t)b*64*HW + hwb + w4*32;
  #pragma unroll
  for (int po=0;po<4;po++)
    #pragma unroll
    for (int j=0;j<4;j++){
      int oc = po*16 + g*4 + j;
      const float* xs = x + obase + (size_t)oc*HW + c15;
      float* dp = out + obase + (size_t)oc*HW + c15;
      #pragma unroll
      for (int pp=0;pp<2;pp++) dp[pp*16] = xs[pp*16] + acc[pp][po][j];
    }
}

// ================= ffn epilogue GEMM (K=128): out += Wpo * y3g (pre-gated) =================
__global__ __launch_bounds__(256) void k_gemm_ffn(
    const u16* __restrict__ y3g, const u16* __restrict__ Wf, float* __restrict__ out,
    int pxbase, int b0)
{
  __shared__ uint4 lsX[128*16];
  __shared__ uint4 lsW[64*16];
  int tid = threadIdx.x;
  int p0 = pxbase + blockIdx.x*128;
  int b = p0 >> 16, hwb = p0 & 65535;
  int px = tid & 127, hf = tid >> 7;
  {
    const uint4* wsrc = (const uint4*)Wf;
    #pragma unroll
    for (int i=0;i<4;i++){
      int idx = i*256 + tid, row = idx>>4, s = idx&15;
      lsW[row*16 + (s ^ (row&15))] = wsrc[idx];
    }
  }
  const u16* yp = y3g + ((size_t)(b-b0)*128 + hf*64)*HW + hwb + px;
  #pragma unroll
  for (int sl=0; sl<8; sl++){
    u32 wds[4];
    #pragma unroll
    for (int q2=0;q2<4;q2++){
      u16 lo = yp[(size_t)(sl*8+q2*2  )*HW];
      u16 hi = yp[(size_t)(sl*8+q2*2+1)*HW];
      wds[q2] = (u32)lo | ((u32)hi << 16);
    }
    int s = hf*8 + sl;
    lsX[px*16 + (s ^ (px&15))] = make_uint4(wds[0],wds[1],wds[2],wds[3]);
  }
  __syncthreads();
  int w4 = tid>>6, l = tid&63, g = l>>4, c15 = l&15;
  f32x4 acc[2][4];
  #pragma unroll
  for (int pp=0;pp<2;pp++)
    #pragma unroll
    for (int po=0;po<4;po++) acc[pp][po] = (f32x4){0.f,0.f,0.f,0.f};
  #pragma unroll
  for (int kk=0; kk<4; kk++){
    v8s wf[4], xf[2];
    #pragma unroll
    for (int po=0;po<4;po++){ int row = po*16 + c15; wf[po] = as8(lsW[row*16 + ((kk*4+g) ^ (row&15))]); }
    #pragma unroll
    for (int pp=0;pp<2;pp++){ int row = w4*32 + pp*16 + c15; xf[pp] = as8(lsX[row*16 + ((kk*4+g) ^ (row&15))]); }
    #pragma unroll
    for (int pp=0;pp<2;pp++)
      #pragma unroll
      for (int po=0;po<4;po++)
        acc[pp][po] = __builtin_amdgcn_mfma_f32_16x16x32_bf16(wf[po], xf[pp], acc[pp][po], 0,0,0);
  }
  size_t obase = (size_t)b*64*HW + hwb + w4*32;
  #pragma unroll
  for (int po=0;po<4;po++)
    #pragma unroll
    for (int j=0;j<4;j++){
      int oc = po*16 + g*4 + j;
      float* dp = out + obase + (size_t)oc*HW + c15;
      #pragma unroll
      for (int pp=0;pp<2;pp++) dp[pp*16] = dp[pp*16] + acc[pp][po][j];
    }
}

// ================= dw3x3 row-of-8 accumulate helper =================
__device__ __forceinline__ void dw8_acc(const u16* __restrict__ sp, const float* __restrict__ w9,
                                        int h, int w8, float acc[8])
{
  #pragma unroll
  for (int r=0;r<3;r++){
    int hh = h + r - 1;
    if (hh < 0 || hh > 255) continue;
    const u16* rp = sp + hh*256 + w8;
    uint4 u = *(const uint4*)rp;
    float vm[10];
    vm[0] = (w8 > 0) ? bf2f(rp[-1]) : 0.f;
    vm[1]=bf2f((u16)(u.x&0xffff)); vm[2]=bf2f((u16)(u.x>>16));
    vm[3]=bf2f((u16)(u.y&0xffff)); vm[4]=bf2f((u16)(u.y>>16));
    vm[5]=bf2f((u16)(u.z&0xffff)); vm[6]=bf2f((u16)(u.z>>16));
    vm[7]=bf2f((u16)(u.w&0xffff)); vm[8]=bf2f((u16)(u.w>>16));
    vm[9] = (w8 < 248) ? bf2f(rp[8]) : 0.f;
    float wa = w9[r*3], wb = w9[r*3+1], wc = w9[r*3+2];
    #pragma unroll
    for (int j=0;j<8;j++) acc[j] += vm[j]*wa + vm[j+1]*wb + vm[j+2]*wc;
  }
}

// ================= depthwise 3x3, 8px/thread (attention v branch) =================
__global__ __launch_bounds__(256) void k_dw8(
    const u16* __restrict__ src, const float* __restrict__ wgt, int c0,
    u16* __restrict__ dst, int cmask, int lg, int dstCd, int dstOff)
{
  int t = blockIdx.x*256 + threadIdx.x;
  int w8 = (t & 31)*8, h = (t>>5) & 255;
  int plane = t >> 13;
  int c = plane & cmask, b = plane >> lg;
  const u16* sp = src + (size_t)plane*HW;
  float acc[8] = {0,0,0,0,0,0,0,0};
  dw8_acc(sp, wgt + (size_t)(c0+c)*9, h, w8, acc);
  uint4 pkv;
  pkv.x = pk2(acc[0],acc[1]); pkv.y = pk2(acc[2],acc[3]);
  pkv.z = pk2(acc[4],acc[5]); pkv.w = pk2(acc[6],acc[7]);
  *(uint4*)(dst + ((size_t)(b*dstCd + dstOff + c))*HW + h*256 + w8) = pkv;
}

// ================= DFFN: dw3x3 on ch c and c+128 + GELU gate -> 128-ch Y3g =================
__global__ __launch_bounds__(256) void k_dw8g(
    const u16* __restrict__ Y0, const float* __restrict__ wgt, u16* __restrict__ Y3g)
{
  int t = blockIdx.x*256 + threadIdx.x;
  int w8 = (t & 31)*8, h = (t>>5) & 255;
  int pc = t >> 13;                 // 0..255
  int c = pc & 127, bl = pc >> 7;
  const u16* spA = Y0 + ((size_t)(bl*256 + c      ))*HW;
  const u16* spG = Y0 + ((size_t)(bl*256 + 128 + c))*HW;
  float aA[8] = {0,0,0,0,0,0,0,0};
  float aG[8] = {0,0,0,0,0,0,0,0};
  dw8_acc(spA, wgt + (size_t)c*9,       h, w8, aA);
  dw8_acc(spG, wgt + (size_t)(128+c)*9, h, w8, aG);
  float r[8];
  #pragma unroll
  for (int j=0;j<8;j++) r[j] = gelu_exact(aA[j]) * aG[j];
  uint4 pkv;
  pkv.x = pk2(r[0],r[1]); pkv.y = pk2(r[2],r[3]);
  pkv.z = pk2(r[4],r[5]); pkv.w = pk2(r[6],r[7]);
  *(uint4*)(Y3g + ((size_t)(bl*128 + c))*HW + h*256 + w8) = pkv;
}

// ================= dw3x3 of one row-of-8 to LDS (attention q/k path) =================
__device__ __forceinline__ void dw_row8_lds(const u16* __restrict__ plane, const float* __restrict__ w9,
                                            int h, int w8, float* __restrict__ dstLds)
{
  float acc[8] = {0,0,0,0,0,0,0,0};
  dw8_acc(plane, w9, h, w8, acc);
  #pragma unroll
  for (int j=0;j<8;j++) dstLds[j] = acc[j];
}

// ================= fused dw(q), dw(k) + per-patch 8x8 circular conv, LDS-staged =================
__global__ __launch_bounds__(256) void k_circqk2(
    const u16* __restrict__ bq, const u16* __restrict__ bk,
    const float* __restrict__ dwq, const float* __restrict__ dwk, int c0,
    u16* __restrict__ oraw, int oc0)
{
  __shared__ float qd[8][288];   // [row][patch*9 + v]
  __shared__ float kd[8][288];
  int tid = threadIdx.x;
  int p = tid & 31, i = tid >> 5;
  int c = blockIdx.y, b = blockIdx.z;
  int h0 = blockIdx.x*8;
  const u16* qp = bq + ((size_t)(b*64+c))*HW;
  const u16* kp = bk + ((size_t)(b*64+c))*HW;
  dw_row8_lds(qp, dwq + (size_t)(c0+c)*9, h0+i, p*8, &qd[i][p*9]);
  dw_row8_lds(kp, dwk + (size_t)(c0+c)*9, h0+i, p*8, &kd[i][p*9]);
  __syncthreads();
  float o[8] = {0,0,0,0,0,0,0,0};
  #pragma unroll
  for (int u=0;u<8;u++){
    float qv[8], kr[8];
    #pragma unroll
    for (int v=0;v<8;v++) qv[v] = qd[u][p*9+v];
    const float* krow = &kd[(i-u)&7][p*9];
    #pragma unroll
    for (int e=0;e<8;e++) kr[e] = krow[e];
    #pragma unroll
    for (int v=0;v<8;v++){
      float qq = qv[v];
      #pragma unroll
      for (int j=0;j<8;j++) o[j] += qq * kr[(j-v)&7];
    }
  }
  u16* op = oraw + ((size_t)(b*128 + oc0 + c))*HW + (size_t)(h0+i)*256 + p*8;
  uint4 pkv;
  pkv.x = pk2(o[0],o[1]); pkv.y = pk2(o[2],o[3]);
  pkv.z = pk2(o[4],o[5]); pkv.w = pk2(o[6],o[7]);
  *(uint4*)op = pkv;
}

// ================= DFFN spectral circular conv (kernel g), LDS-staged, in-place =================
__global__ __launch_bounds__(256) void k_circg2(
    u16* __restrict__ y, const float* __restrict__ g)
{
  __shared__ float yd[8][288];
  __shared__ float gs[64];
  int tid = threadIdx.x;
  int p = tid & 31, i = tid >> 5;
  int c = blockIdx.y, b = blockIdx.z;
  int h0 = blockIdx.x*8;
  u16* plane = y + ((size_t)(b*256+c))*HW;
  {
    const u16* rp = plane + (size_t)(h0+i)*256 + p*8;
    uint4 u = *(const uint4*)rp;
    float* dr = &yd[i][p*9];
    dr[0]=bf2f((u16)(u.x&0xffff)); dr[1]=bf2f((u16)(u.x>>16));
    dr[2]=bf2f((u16)(u.y&0xffff)); dr[3]=bf2f((u16)(u.y>>16));
    dr[4]=bf2f((u16)(u.z&0xffff)); dr[5]=bf2f((u16)(u.z>>16));
    dr[6]=bf2f((u16)(u.w&0xffff)); dr[7]=bf2f((u16)(u.w>>16));
  }
  if (tid < 64) gs[tid] = g[(size_t)c*64 + tid];
  __syncthreads();
  float o[8] = {0,0,0,0,0,0,0,0};
  #pragma unroll
  for (int u=0;u<8;u++){
    float yv[8], gr[8];
    #pragma unroll
    for (int v=0;v<8;v++) yv[v] = yd[u][p*9+v];
    const float* grow = &gs[((i-u)&7)*8];
    #pragma unroll
    for (int e=0;e<8;e++) gr[e] = grow[e];
    #pragma unroll
    for (int v=0;v<8;v++){
      float qq = yv[v];
      #pragma unroll
      for (int j=0;j<8;j++) o[j] += qq * gr[(j-v)&7];
    }
  }
  u16* op = plane + (size_t)(h0+i)*256 + p*8;
  uint4 pkv;
  pkv.x = pk2(o[0],o[1]); pkv.y = pk2(o[2],o[3]);
  pkv.z = pk2(o[4],o[5]); pkv.w = pk2(o[6],o[7]);
  *(uint4*)op = pkv;
}

extern "C" void kernel_launch(void* const* d_in, const int* in_sizes, int n_in,
                              void* d_out, int out_size, void* d_ws, size_t ws_size,
                              hipStream_t stream)
{
  const float* x       = (const float*)d_in[0];
  const float* evt     = (const float*)d_in[1];
  const float* ln1i_w  = (const float*)d_in[2];
  const float* ln1i_b  = (const float*)d_in[3];
  const float* ln1e_w  = (const float*)d_in[4];
  const float* ln1e_b  = (const float*)d_in[5];
  const float* w_q     = (const float*)d_in[6];
  const float* dw_q    = (const float*)d_in[7];
  const float* w_kv    = (const float*)d_in[8];
  const float* dw_kv   = (const float*)d_in[9];
  const float* lnA_w   = (const float*)d_in[10];
  const float* lnA_b   = (const float*)d_in[11];
  const float* w_po_at = (const float*)d_in[12];
  const float* ln2_w   = (const float*)d_in[13];
  const float* ln2_b   = (const float*)d_in[14];
  const float* w_pi    = (const float*)d_in[15];
  const float* fft_par = (const float*)d_in[16];
  const float* dw_ffn  = (const float*)d_in[17];
  const float* w_poffn = (const float*)d_in[18];
  float* out = (float*)d_out;

  char* ws = (char*)d_ws;
  const size_t MiB = 1048576ull;
  u16*   P1   = (u16*)(ws);                    // 32 MiB  (B,64,HW)
  u16*   ORAW = (u16*)(ws + 32*MiB);           // 64 MiB  (B,128,HW)
  u16*   P2   = (u16*)(ws + 96*MiB);           // 32 MiB
  u16*   VBUF = (u16*)(ws + 96*MiB);           // 64 MiB  (B,128,HW) — after P2 dead
  u16*   Y0   = (u16*)(ws);                    // 64 MiB  (2,256,HW) half — after P1/ORAW dead
  u16*   Y3G  = (u16*)(ws + 64*MiB);           // 32 MiB  (2,128,HW) half (gated)
  char* sm = ws + 160*MiB;
  float* G    = (float*)(sm);                  // 64 KiB
  u16* WQF    = (u16*)(sm + 65536);
  u16* WKVF   = (u16*)(sm + 81920);
  u16* WPIF   = (u16*)(sm + 114688);
  u16* WPAF   = (u16*)(sm + 147456);
  u16* WPFF   = (u16*)(sm + 163840);
  float* AQ   = (float*)(sm + 180224);
  float* BQ   = (float*)(sm + 180736);
  float* AKV  = (float*)(sm + 181248);
  float* BKV  = (float*)(sm + 182272);
  float* API  = (float*)(sm + 183296);
  float* BPI  = (float*)(sm + 184320);

  dim3 blk256(256);

  k_prep<<<69, blk256, 0, stream>>>(fft_par, G,
      w_q, ln1i_w, ln1i_b, WQF, AQ, BQ,
      w_kv, ln1e_w, ln1e_b, WKVF, AKV, BKV,
      w_pi, ln2_w, ln2_b, WPIF, API, BPI,
      w_po_at, WPAF, w_poffn, WPFF);

  // ---- attention q,k chunks (stats computed inline) ----
  for (int i=0;i<2;i++){
    GA qa = {x,   WQF,  AQ,  BQ,  P1, 64*i, 0, 64, 0, 0, 1};
    GA ka = {evt, WKVF, AKV, BKV, P2, 64*i, 0, 64, 0, 0, 1};
    k_gemm64<<<dim3(1024,2,1), blk256, 0, stream>>>(qa, ka);
    k_circqk2<<<dim3(32,64,4), blk256, 0, stream>>>(P1, P2, dw_q, dw_kv, 64*i, ORAW, 64*i);
  }
  // ---- v chunks ----
  for (int i=0;i<2;i++){
    GA va = {evt, WKVF, AKV, BKV, P1, 128+64*i, 0, 64, 0, 0, 1};
    k_gemm64<<<dim3(1024,1,1), blk256, 0, stream>>>(va, va);
    k_dw8<<<8192, blk256, 0, stream>>>(P1, dw_kv, 128+64*i, VBUF, 63, 6, 128, 64*i);
  }
  // ---- attn epilogue -> d_out ----
  k_gemm_attn<<<2048, blk256, 0, stream>>>(x, ORAW, VBUF, lnA_w, lnA_b, WPAF, out);

  // ---- DFFN in two batch-halves: pi-GEMM(nz=4, stats inline) -> circ -> dw+gate -> ffn-GEMM ----
  for (int h=0;h<2;h++){
    GA pa = {out, WPIF, API, BPI, Y0, 0, 0, 256, 2*h, h*131072, 4};
    k_gemm64<<<dim3(512,1,1), blk256, 0, stream>>>(pa, pa);
    k_circg2<<<dim3(32,256,2), blk256, 0, stream>>>(Y0, G);
    k_dw8g<<<8192, blk256, 0, stream>>>(Y0, dw_ffn, Y3G);
    k_gemm_ffn<<<1024, blk256, 0, stream>>>(Y3G, WPFF, out, h*131072, 2*h);
  }
}